// Round 6
// baseline (280.576 us; speedup 1.0000x reference)
//
#include <hip/hip_runtime.h>
#include <hip/hip_fp16.h>

typedef _Float16 f16x8 __attribute__((ext_vector_type(8)));
typedef _Float16 f16x4 __attribute__((ext_vector_type(4)));
typedef float f32x4_t __attribute__((ext_vector_type(4)));

// ---------------- fused f32 -> f16 conversion (8 tensors, one launch) ----------------
struct CvtArgs {
  const float* src[8];
  _Float16* dst[8];
  int n4[8];
};

__global__ __launch_bounds__(256) void cvt_all(CvtArgs a) {
  const int t = blockIdx.y;
  const float4* __restrict__ in = (const float4*)a.src[t];
  f16x4* __restrict__ out = (f16x4*)a.dst[t];
  const int n4 = a.n4[t];
  const int stride = gridDim.x * blockDim.x;
  for (int i = blockIdx.x * blockDim.x + threadIdx.x; i < n4; i += stride) {
    float4 v = in[i];
    f16x4 h;
    h[0] = (_Float16)v.x; h[1] = (_Float16)v.y; h[2] = (_Float16)v.z; h[3] = (_Float16)v.w;
    out[i] = h;
  }
}

// ---------------- NT GEMM tile: C[128,64] = A[128,1024] @ W[64,1024]^T + b --------
// BK=64, double-buffered LDS, ONE barrier per K-step, 2-deep global prefetch.
// 4 waves (2x2): per-wave 64x32 output = 4x2 frags, 16 MFMA / K-step.
template <bool OUTH>
__device__ __forceinline__ void gemm_tile64(const _Float16* __restrict__ A,
                                            const _Float16* __restrict__ W,
                                            const float* __restrict__ bias,
                                            void* __restrict__ Cv, int tm, int tn) {
  __shared__ _Float16 Ash[2][128][72];  // 64 + 8 pad: <=2-way bank conflicts on b128
  __shared__ _Float16 Bsh[2][64][72];

  const int tid = threadIdx.x;
  const int lane = tid & 63;
  const int wave = tid >> 6;
  const int wr = wave >> 1;  // 0..1
  const int wc = wave & 1;   // 0..1

  // staging granules: thread covers (row = tid>>3 (+32k), col = (tid&7)*8)
  const int srow = tid >> 3;       // 0..31
  const int scol = (tid & 7) * 8;  // 0..56
  const _Float16* Ag = A + (size_t)(tm + srow) * 1024 + scol;
  const _Float16* Bg = W + (size_t)(tn + srow) * 1024 + scol;

  f32x4_t acc[4][2];
#pragma unroll
  for (int m = 0; m < 4; ++m)
#pragma unroll
    for (int n = 0; n < 2; ++n) acc[m][n] = (f32x4_t){0.f, 0.f, 0.f, 0.f};

  uint4 ra[4], rb[2];

  // prologue: stage kt=0, prefetch kt=1
#pragma unroll
  for (int i = 0; i < 4; ++i) ra[i] = *(const uint4*)(Ag + (size_t)(i * 32) * 1024);
#pragma unroll
  for (int i = 0; i < 2; ++i) rb[i] = *(const uint4*)(Bg + (size_t)(i * 32) * 1024);
#pragma unroll
  for (int i = 0; i < 4; ++i) *(uint4*)&Ash[0][srow + i * 32][scol] = ra[i];
#pragma unroll
  for (int i = 0; i < 2; ++i) *(uint4*)&Bsh[0][srow + i * 32][scol] = rb[i];
#pragma unroll
  for (int i = 0; i < 4; ++i) ra[i] = *(const uint4*)(Ag + (size_t)(i * 32) * 1024 + 64);
#pragma unroll
  for (int i = 0; i < 2; ++i) rb[i] = *(const uint4*)(Bg + (size_t)(i * 32) * 1024 + 64);
  __syncthreads();

  const int fr = lane & 15;
  const int kc = (lane >> 4) * 8;

#pragma unroll 1
  for (int t = 0; t < 16; ++t) {
    const int cur = t & 1;
    f16x8 af[2][4], bf[2][2];
#pragma unroll
    for (int ks = 0; ks < 2; ++ks) {
#pragma unroll
      for (int m = 0; m < 4; ++m)
        af[ks][m] = *(const f16x8*)&Ash[cur][wr * 64 + m * 16 + fr][ks * 32 + kc];
#pragma unroll
      for (int n = 0; n < 2; ++n)
        bf[ks][n] = *(const f16x8*)&Bsh[cur][wc * 32 + n * 16 + fr][ks * 32 + kc];
    }
#pragma unroll
    for (int ks = 0; ks < 2; ++ks)
#pragma unroll
      for (int m = 0; m < 4; ++m)
#pragma unroll
        for (int n = 0; n < 2; ++n)
          acc[m][n] =
              __builtin_amdgcn_mfma_f32_16x16x32_f16(af[ks][m], bf[ks][n], acc[m][n], 0, 0, 0);
    if (t < 15) {  // write prefetched tile t+1 into the other buffer
#pragma unroll
      for (int i = 0; i < 4; ++i) *(uint4*)&Ash[cur ^ 1][srow + i * 32][scol] = ra[i];
#pragma unroll
      for (int i = 0; i < 2; ++i) *(uint4*)&Bsh[cur ^ 1][srow + i * 32][scol] = rb[i];
    }
    if (t < 14) {  // prefetch tile t+2
#pragma unroll
      for (int i = 0; i < 4; ++i)
        ra[i] = *(const uint4*)(Ag + (size_t)(i * 32) * 1024 + (t + 2) * 64);
#pragma unroll
      for (int i = 0; i < 2; ++i)
        rb[i] = *(const uint4*)(Bg + (size_t)(i * 32) * 1024 + (t + 2) * 64);
    }
    __syncthreads();
  }

  // epilogue: C/D layout col=lane&15, row=(lane>>4)*4+reg
  const int cr = (lane >> 4) * 4;
  const int cc = lane & 15;
#pragma unroll
  for (int m = 0; m < 4; ++m) {
#pragma unroll
    for (int n = 0; n < 2; ++n) {
      const int col = tn + wc * 32 + n * 16 + cc;
      const float bv = bias[col];
#pragma unroll
      for (int r = 0; r < 4; ++r) {
        const int row = tm + wr * 64 + m * 16 + cr + r;
        float v = acc[m][n][r] + bv;
        if (OUTH)
          ((_Float16*)Cv)[(size_t)row * 1024 + col] = (_Float16)v;
        else
          ((float*)Cv)[(size_t)row * 1024 + col] = v;
      }
    }
  }
}

// ---------------- launch 2: fill(attn h<8) FIRST, then Q,K,V GEMMs ----------------
// flat grid 1024: [0,256) fill, [256,768) Q, [768,896) K, [896,1024) V
__global__ __launch_bounds__(256) void gemm_qkv_fill(
    const _Float16* __restrict__ hV, const _Float16* __restrict__ hL,
    const _Float16* __restrict__ hWq, const _Float16* __restrict__ hWk,
    const _Float16* __restrict__ hWv,
    const float* __restrict__ bq, const float* __restrict__ bk, const float* __restrict__ bv,
    _Float16* __restrict__ Qh, _Float16* __restrict__ Kh, _Float16* __restrict__ Vh,
    float* __restrict__ attn) {
  int b = blockIdx.x;
  if (b < 256) {  // zero attn[0:8,:,:] = 134 MB, dispatched first -> co-runs with GEMM
    float4* base = (float4*)attn + (size_t)b * 32768;
    const float4 z4 = {0.f, 0.f, 0.f, 0.f};
    for (int i = threadIdx.x; i < 32768; i += 256) base[i] = z4;
    return;
  }
  b -= 256;
  if (b < 512) {
    gemm_tile64<true>(hV, hWq, bq, (void*)Qh, (b >> 4) * 128, (b & 15) * 64);
    return;
  }
  b -= 512;
  if (b < 128) {
    gemm_tile64<true>(hL, hWk, bk, (void*)Kh, (b >> 4) * 128, (b & 15) * 64);
    return;
  }
  b -= 128;
  gemm_tile64<true>(hL, hWv, bv, (void*)Vh, (b >> 4) * 128, (b & 15) * 64);
}

// ---------------- launch 4: Wo GEMM (f16 out), 512 blocks ----------------
__global__ __launch_bounds__(256) void gemm_wo(
    const _Float16* __restrict__ ctx, const _Float16* __restrict__ hWo,
    const float* __restrict__ bo, _Float16* __restrict__ outh) {
  const int b = blockIdx.x;
  gemm_tile64<true>(ctx, hWo, bo, (void*)outh, (b >> 4) * 128, (b & 15) * 64);
}

// ---------------- launch 5: skip-fill(attn h>=8) FIRST, then mu/logvar ----------------
// flat grid 1280: [0,256) skip-fill, [256,768) mu, [768,1280) logvar
__global__ __launch_bounds__(256) void gemm_mv_fill(
    const _Float16* __restrict__ outh,
    const _Float16* __restrict__ hWm, const _Float16* __restrict__ hWv2,
    const float* __restrict__ bm, const float* __restrict__ bv2,
    float* __restrict__ mu, float* __restrict__ logv, float* __restrict__ attn) {
  int b = blockIdx.x;
  if (b < 256) {  // zero attn[8:16] except the 32-col nonzero block (already written)
    const int wave = threadIdx.x >> 6;
    const int lane = threadIdx.x & 63;
    const float4 z4 = {0.f, 0.f, 0.f, 0.f};
    for (int i = 0; i < 32; ++i) {
      const int rowIdx = b * 128 + i * 4 + wave;  // 0..32767 over (h-8, p)
      const int p = rowIdx & 4095;
      const int g8 = (p >> 7) * 8;  // float4 index of nonzero 32-col block
      float4* row = (float4*)(attn + ((size_t)(8 + (rowIdx >> 12)) * 4096 + p) * 1024);
      for (int c = lane; c < 256; c += 64)
        if (c < g8 || c >= g8 + 8) row[c] = z4;
    }
    return;
  }
  b -= 256;
  if (b < 512) {
    gemm_tile64<false>(outh, hWm, bm, (void*)mu, (b >> 4) * 128, (b & 15) * 64);
    return;
  }
  b -= 512;
  gemm_tile64<false>(outh, hWv2, bv2, (void*)logv, (b >> 4) * 128, (b & 15) * 64);
}

// ---------------- block-diagonal attention (f16 Q/K/V inputs) ----------------
__global__ __launch_bounds__(256) void attn_kernel(
    const _Float16* __restrict__ Qh, const _Float16* __restrict__ Kh,
    const _Float16* __restrict__ Vh,
    float* __restrict__ attn_out,  // [16,4096,1024] slice of d_out
    _Float16* __restrict__ ctx) {  // [4096,1024] fp16
  const int g = blockIdx.x;
  const int h = blockIdx.y;

  __shared__ float Ksh[32][68];
  __shared__ float Vsh[32][68];
  __shared__ float Arow[128][33];

  const int tid = threadIdx.x;
  {
    const int r = tid >> 3, c8 = (tid & 7) * 8;
    f16x8 kv = *(const f16x8*)(Kh + (size_t)(g * 32 + r) * 1024 + h * 64 + c8);
    f16x8 vv = *(const f16x8*)(Vh + (size_t)(g * 32 + r) * 1024 + h * 64 + c8);
#pragma unroll
    for (int j = 0; j < 8; ++j) {
      Ksh[r][c8 + j] = (float)kv[j];
      Vsh[r][c8 + j] = (float)vv[j];
    }
  }
  __syncthreads();

  const int p = tid >> 1;
  const int half = tid & 1;

  float qf[64];
  const f16x8* qp = (const f16x8*)(Qh + (size_t)(g * 128 + p) * 1024 + h * 64);
#pragma unroll
  for (int i = 0; i < 8; ++i) {
    f16x8 v = qp[i];
#pragma unroll
    for (int j = 0; j < 8; ++j) qf[i * 8 + j] = (float)v[j];
  }

  float s[16];
#pragma unroll
  for (int j = 0; j < 16; ++j) {
    const int t = half * 16 + j;
    float acc = 0.f;
#pragma unroll
    for (int d = 0; d < 64; ++d) acc += qf[d] * Ksh[t][d];
    s[j] = acc * 0.125f;  // 1/sqrt(64)
  }

  // softmax over 32 = 16 local + partner lane (tid^1 shares row p)
  float m = s[0];
#pragma unroll
  for (int j = 1; j < 16; ++j) m = fmaxf(m, s[j]);
  m = fmaxf(m, __shfl_xor(m, 1));
  float e[16];
  float sum = 0.f;
#pragma unroll
  for (int j = 0; j < 16; ++j) {
    e[j] = __expf(s[j] - m);
    sum += e[j];
  }
  sum += __shfl_xor(sum, 1);
  const float inv = 1.0f / sum;

  float* arow_out =
      attn_out + (size_t)h * 4096 * 1024 + (size_t)(g * 128 + p) * 1024 + g * 32 + half * 16;
#pragma unroll
  for (int j = 0; j < 16; ++j) {
    float a = e[j] * inv;
    arow_out[j] = a;
    Arow[p][half * 16 + j] = a;
  }
  __syncthreads();

  // PV: ctx[p][half*32 + 0..31]
  float4 acc4[8];
#pragma unroll
  for (int i = 0; i < 8; ++i) acc4[i] = (float4){0.f, 0.f, 0.f, 0.f};
#pragma unroll
  for (int t = 0; t < 32; ++t) {
    const float av = Arow[p][t];
#pragma unroll
    for (int d4 = 0; d4 < 8; ++d4) {
      float4 v = *(const float4*)&Vsh[t][half * 32 + d4 * 4];
      acc4[d4].x += av * v.x;
      acc4[d4].y += av * v.y;
      acc4[d4].z += av * v.z;
      acc4[d4].w += av * v.w;
    }
  }
  _Float16* crow = ctx + (size_t)(g * 128 + p) * 1024 + h * 64 + half * 32;
#pragma unroll
  for (int i = 0; i < 4; ++i) {
    f16x8 hv;
    float4 lo = acc4[i * 2], hi = acc4[i * 2 + 1];
    hv[0] = (_Float16)lo.x; hv[1] = (_Float16)lo.y;
    hv[2] = (_Float16)lo.z; hv[3] = (_Float16)lo.w;
    hv[4] = (_Float16)hi.x; hv[5] = (_Float16)hi.y;
    hv[6] = (_Float16)hi.z; hv[7] = (_Float16)hi.w;
    *(f16x8*)&crow[i * 8] = hv;
  }
}

// ---------------- launch ----------------
extern "C" void kernel_launch(void* const* d_in, const int* in_sizes, int n_in,
                              void* d_out, int out_size, void* d_ws, size_t ws_size,
                              hipStream_t stream) {
  const float* V_token = (const float*)d_in[0];
  const float* L_token = (const float*)d_in[1];
  const float* Wq_w = (const float*)d_in[4];
  const float* Wq_b = (const float*)d_in[5];
  const float* Wk_w = (const float*)d_in[6];
  const float* Wk_b = (const float*)d_in[7];
  const float* Wv_w = (const float*)d_in[8];
  const float* Wv_b = (const float*)d_in[9];
  const float* Wo_w = (const float*)d_in[10];
  const float* Wo_b = (const float*)d_in[11];
  const float* Wm_w = (const float*)d_in[12];
  const float* Wm_b = (const float*)d_in[13];
  const float* Wv2_w = (const float*)d_in[14];
  const float* Wv2_b = (const float*)d_in[15];

  char* ws = (char*)d_ws;
  _Float16* hV = (_Float16*)ws;   ws += (size_t)4096 * 1024 * 2;
  _Float16* hL = (_Float16*)ws;   ws += (size_t)1024 * 1024 * 2;
  _Float16* hWq = (_Float16*)ws;  ws += (size_t)1024 * 1024 * 2;
  _Float16* hWk = (_Float16*)ws;  ws += (size_t)1024 * 1024 * 2;
  _Float16* hWv = (_Float16*)ws;  ws += (size_t)1024 * 1024 * 2;
  _Float16* hWo = (_Float16*)ws;  ws += (size_t)1024 * 1024 * 2;
  _Float16* hWm = (_Float16*)ws;  ws += (size_t)1024 * 1024 * 2;
  _Float16* hWv2 = (_Float16*)ws; ws += (size_t)1024 * 1024 * 2;
  _Float16* Qh = (_Float16*)ws;   ws += (size_t)4096 * 1024 * 2;
  _Float16* Kh = (_Float16*)ws;   ws += (size_t)1024 * 1024 * 2;
  _Float16* Vh = (_Float16*)ws;   ws += (size_t)1024 * 1024 * 2;
  _Float16* ctx = (_Float16*)ws;  ws += (size_t)4096 * 1024 * 2;
  _Float16* outh = (_Float16*)ws; ws += (size_t)4096 * 1024 * 2;

  float* mu = (float*)d_out;
  float* logv = mu + (size_t)4096 * 1024;
  float* attn = mu + (size_t)2 * 4096 * 1024;

  // 1: all f32->f16 conversions in one launch
  CvtArgs ca;
  ca.src[0] = V_token; ca.dst[0] = hV;  ca.n4[0] = 4096 * 1024 / 4;
  ca.src[1] = L_token; ca.dst[1] = hL;  ca.n4[1] = 1024 * 1024 / 4;
  ca.src[2] = Wq_w;  ca.dst[2] = hWq;  ca.n4[2] = 1024 * 1024 / 4;
  ca.src[3] = Wk_w;  ca.dst[3] = hWk;  ca.n4[3] = 1024 * 1024 / 4;
  ca.src[4] = Wv_w;  ca.dst[4] = hWv;  ca.n4[4] = 1024 * 1024 / 4;
  ca.src[5] = Wo_w;  ca.dst[5] = hWo;  ca.n4[5] = 1024 * 1024 / 4;
  ca.src[6] = Wm_w;  ca.dst[6] = hWm;  ca.n4[6] = 1024 * 1024 / 4;
  ca.src[7] = Wv2_w; ca.dst[7] = hWv2; ca.n4[7] = 1024 * 1024 / 4;
  hipLaunchKernelGGL(cvt_all, dim3(128, 8), dim3(256), 0, stream, ca);

  // 2: fill attn[0:8] (dispatched first) + Q,K,V GEMMs
  hipLaunchKernelGGL(gemm_qkv_fill, dim3(1024), dim3(256), 0, stream,
                     hV, hL, hWq, hWk, hWv, Wq_b, Wk_b, Wv_b, Qh, Kh, Vh, attn);

  // 3: attention -> attn nonzero blocks (d_out) + ctx (fp16)
  hipLaunchKernelGGL(attn_kernel, dim3(32, 16), dim3(256), 0, stream, Qh, Kh, Vh, attn, ctx);

  // 4: out = ctx @ Wo^T + bo (fp16 out)
  hipLaunchKernelGGL(gemm_wo, dim3(512), dim3(256), 0, stream, ctx, hWo, Wo_b, outh);

  // 5: skip-fill attn[8:16] (dispatched first) + mu/log_var GEMMs
  hipLaunchKernelGGL(gemm_mv_fill, dim3(1280), dim3(256), 0, stream,
                     outh, hWm, hWv2, Wm_b, Wv2_b, mu, logv, attn);
}

// Round 8
// 175.551 us; speedup vs baseline: 1.5983x; 1.5983x over previous
//
#include <hip/hip_runtime.h>
#include <hip/hip_fp16.h>

typedef _Float16 f16x8 __attribute__((ext_vector_type(8)));
typedef _Float16 f16x4 __attribute__((ext_vector_type(4)));
typedef float f32x4_t __attribute__((ext_vector_type(4)));

// async global->LDS, 16B per lane; LDS dest = wave-uniform base + lane*16
__device__ __forceinline__ void async16(void* lds, const void* g) {
  __builtin_amdgcn_global_load_lds(
      (const __attribute__((address_space(1))) unsigned int*)g,
      (__attribute__((address_space(3))) unsigned int*)lds, 16, 0, 0);
}

// ---------------- fused f32 -> f16 conversion (8 tensors, one launch) ----------------
struct CvtArgs {
  const float* src[8];
  _Float16* dst[8];
  int n4[8];
};

__global__ __launch_bounds__(256) void cvt_all(CvtArgs a) {
  const int t = blockIdx.y;
  const float4* __restrict__ in = (const float4*)a.src[t];
  f16x4* __restrict__ out = (f16x4*)a.dst[t];
  const int n4 = a.n4[t];
  const int stride = gridDim.x * blockDim.x;
  for (int i = blockIdx.x * blockDim.x + threadIdx.x; i < n4; i += stride) {
    float4 v = in[i];
    f16x4 h;
    h[0] = (_Float16)v.x; h[1] = (_Float16)v.y; h[2] = (_Float16)v.z; h[3] = (_Float16)v.w;
    out[i] = h;
  }
}

// ---------------- NT GEMM tile (m97 structure): C[128,128] = A @ W^T + b ----------
// BK=32, LINEAR LDS [128][32] f16 (8KB each), global_load_lds width-16 staging,
// single buffer, 2 barriers per K-step. 4 waves (2x2), 4x4 16x16x32 frags/wave.
template <bool OUTH>
__device__ __forceinline__ void gemm_tile128(const _Float16* __restrict__ A,
                                             const _Float16* __restrict__ W,
                                             const float* __restrict__ bias,
                                             void* __restrict__ Cv, int tm, int tn) {
  __shared__ _Float16 Ash[128][32];
  __shared__ _Float16 Bsh[128][32];

  const int tid = threadIdx.x;
  const int lane = tid & 63;
  const int wave = tid >> 6;
  const int wr = wave >> 1;
  const int wc = wave & 1;

  // staging map: wave w, issue i covers rows w*32+i*16 .. +15 of the tile;
  // lane l -> row +(l>>2), 16B slot (l&3). LDS row = 64B so 1KB = 16 rows.
  const int grow = wave * 32 + (lane >> 2);
  const int gcol = (lane & 3) * 8;
  const _Float16* Ag0 = A + (size_t)(tm + grow) * 1024 + gcol;
  const _Float16* Ag1 = Ag0 + (size_t)16 * 1024;
  const _Float16* Bg0 = W + (size_t)(tn + grow) * 1024 + gcol;
  const _Float16* Bg1 = Bg0 + (size_t)16 * 1024;
  void* la0 = &Ash[wave * 32][0];
  void* la1 = &Ash[wave * 32 + 16][0];
  void* lb0 = &Bsh[wave * 32][0];
  void* lb1 = &Bsh[wave * 32 + 16][0];

  f32x4_t acc[4][4];
#pragma unroll
  for (int m = 0; m < 4; ++m)
#pragma unroll
    for (int n = 0; n < 4; ++n) acc[m][n] = (f32x4_t){0.f, 0.f, 0.f, 0.f};

  const int fr = lane & 15;
  const int kc = (lane >> 4) * 8;

#pragma unroll 1
  for (int kt = 0; kt < 32; ++kt) {
    const int ko = kt * 32;
    __syncthreads();  // previous compute done reading LDS
    async16(la0, Ag0 + ko);
    async16(la1, Ag1 + ko);
    async16(lb0, Bg0 + ko);
    async16(lb1, Bg1 + ko);
    __syncthreads();  // compiler drains vmcnt before s_barrier

    f16x8 af[4], bf[4];
#pragma unroll
    for (int m = 0; m < 4; ++m) af[m] = *(const f16x8*)&Ash[wr * 64 + m * 16 + fr][kc];
#pragma unroll
    for (int n = 0; n < 4; ++n) bf[n] = *(const f16x8*)&Bsh[wc * 64 + n * 16 + fr][kc];
#pragma unroll
    for (int m = 0; m < 4; ++m)
#pragma unroll
      for (int n = 0; n < 4; ++n)
        acc[m][n] = __builtin_amdgcn_mfma_f32_16x16x32_f16(af[m], bf[n], acc[m][n], 0, 0, 0);
  }

  // epilogue: C/D layout col=lane&15, row=(lane>>4)*4+reg
  const int cr = (lane >> 4) * 4;
  const int cc = lane & 15;
#pragma unroll
  for (int m = 0; m < 4; ++m) {
#pragma unroll
    for (int n = 0; n < 4; ++n) {
      const int col = tn + wc * 64 + n * 16 + cc;
      const float bv = bias[col];
#pragma unroll
      for (int r = 0; r < 4; ++r) {
        const int row = tm + wr * 64 + m * 16 + cr + r;
        float v = acc[m][n][r] + bv;
        if (OUTH)
          ((_Float16*)Cv)[(size_t)row * 1024 + col] = (_Float16)v;
        else
          ((float*)Cv)[(size_t)row * 1024 + col] = v;
      }
    }
  }
}

// ---------------- launch 2: fill(attn h<8) FIRST, then Q,K,V GEMMs ----------------
// flat grid 640: [0,256) fill, [256,512) Q (32x8 tiles), [512,576) K, [576,640) V
__global__ __launch_bounds__(256) void gemm_qkv_fill(
    const _Float16* __restrict__ hV, const _Float16* __restrict__ hL,
    const _Float16* __restrict__ hWq, const _Float16* __restrict__ hWk,
    const _Float16* __restrict__ hWv,
    const float* __restrict__ bq, const float* __restrict__ bk, const float* __restrict__ bv,
    _Float16* __restrict__ Qh, _Float16* __restrict__ Kh, _Float16* __restrict__ Vh,
    float* __restrict__ attn) {
  int b = blockIdx.x;
  if (b < 256) {  // zero attn[0:8,:,:] = 134 MB; dispatched first -> co-runs with GEMMs
    float4* base = (float4*)attn + (size_t)b * 32768;
    const float4 z4 = {0.f, 0.f, 0.f, 0.f};
    for (int i = threadIdx.x; i < 32768; i += 256) base[i] = z4;
    return;
  }
  b -= 256;
  if (b < 256) {
    gemm_tile128<true>(hV, hWq, bq, (void*)Qh, (b >> 3) * 128, (b & 7) * 128);
    return;
  }
  b -= 256;
  if (b < 64) {
    gemm_tile128<true>(hL, hWk, bk, (void*)Kh, (b >> 3) * 128, (b & 7) * 128);
    return;
  }
  b -= 64;
  gemm_tile128<true>(hL, hWv, bv, (void*)Vh, (b >> 3) * 128, (b & 7) * 128);
}

// ---------------- launch 4: Wo GEMM (f16 out), 256 blocks ----------------
__global__ __launch_bounds__(256) void gemm_wo(
    const _Float16* __restrict__ ctx, const _Float16* __restrict__ hWo,
    const float* __restrict__ bo, _Float16* __restrict__ outh) {
  const int b = blockIdx.x;
  gemm_tile128<true>(ctx, hWo, bo, (void*)outh, (b >> 3) * 128, (b & 7) * 128);
}

// ---------------- launch 5: skip-fill(attn h>=8) FIRST, then mu/logvar ----------------
// flat grid 768: [0,256) skip-fill, [256,512) mu, [512,768) logvar
__global__ __launch_bounds__(256) void gemm_mv_fill(
    const _Float16* __restrict__ outh,
    const _Float16* __restrict__ hWm, const _Float16* __restrict__ hWv2,
    const float* __restrict__ bm, const float* __restrict__ bv2,
    float* __restrict__ mu, float* __restrict__ logv, float* __restrict__ attn) {
  int b = blockIdx.x;
  if (b < 256) {  // zero attn[8:16] except the 32-col nonzero block (written by attn)
    const int wave = threadIdx.x >> 6;
    const int lane = threadIdx.x & 63;
    const float4 z4 = {0.f, 0.f, 0.f, 0.f};
    for (int i = 0; i < 32; ++i) {
      const int rowIdx = b * 128 + i * 4 + wave;  // 0..32767 over (h-8, p)
      const int p = rowIdx & 4095;
      const int g8 = (p >> 7) * 8;  // float4 index of nonzero 32-col block
      float4* row = (float4*)(attn + ((size_t)(8 + (rowIdx >> 12)) * 4096 + p) * 1024);
      for (int c = lane; c < 256; c += 64)
        if (c < g8 || c >= g8 + 8) row[c] = z4;
    }
    return;
  }
  b -= 256;
  if (b < 256) {
    gemm_tile128<false>(outh, hWm, bm, (void*)mu, (b >> 3) * 128, (b & 7) * 128);
    return;
  }
  b -= 256;
  gemm_tile128<false>(outh, hWv2, bv2, (void*)logv, (b >> 3) * 128, (b & 7) * 128);
}

// ---------------- block-diagonal attention (f16 Q/K/V inputs) ----------------
__global__ __launch_bounds__(256) void attn_kernel(
    const _Float16* __restrict__ Qh, const _Float16* __restrict__ Kh,
    const _Float16* __restrict__ Vh,
    float* __restrict__ attn_out,  // [16,4096,1024] slice of d_out
    _Float16* __restrict__ ctx) {  // [4096,1024] fp16
  const int g = blockIdx.x;
  const int h = blockIdx.y;

  __shared__ float Ksh[32][68];
  __shared__ float Vsh[32][68];
  __shared__ float Arow[128][33];

  const int tid = threadIdx.x;
  {
    const int r = tid >> 3, c8 = (tid & 7) * 8;
    f16x8 kv = *(const f16x8*)(Kh + (size_t)(g * 32 + r) * 1024 + h * 64 + c8);
    f16x8 vv = *(const f16x8*)(Vh + (size_t)(g * 32 + r) * 1024 + h * 64 + c8);
#pragma unroll
    for (int j = 0; j < 8; ++j) {
      Ksh[r][c8 + j] = (float)kv[j];
      Vsh[r][c8 + j] = (float)vv[j];
    }
  }
  __syncthreads();

  const int p = tid >> 1;
  const int half = tid & 1;

  float qf[64];
  const f16x8* qp = (const f16x8*)(Qh + (size_t)(g * 128 + p) * 1024 + h * 64);
#pragma unroll
  for (int i = 0; i < 8; ++i) {
    f16x8 v = qp[i];
#pragma unroll
    for (int j = 0; j < 8; ++j) qf[i * 8 + j] = (float)v[j];
  }

  float s[16];
#pragma unroll
  for (int j = 0; j < 16; ++j) {
    const int t = half * 16 + j;
    float acc = 0.f;
#pragma unroll
    for (int d = 0; d < 64; ++d) acc += qf[d] * Ksh[t][d];
    s[j] = acc * 0.125f;  // 1/sqrt(64)
  }

  float m = s[0];
#pragma unroll
  for (int j = 1; j < 16; ++j) m = fmaxf(m, s[j]);
  m = fmaxf(m, __shfl_xor(m, 1));
  float e[16];
  float sum = 0.f;
#pragma unroll
  for (int j = 0; j < 16; ++j) {
    e[j] = __expf(s[j] - m);
    sum += e[j];
  }
  sum += __shfl_xor(sum, 1);
  const float inv = 1.0f / sum;

  float* arow_out =
      attn_out + (size_t)h * 4096 * 1024 + (size_t)(g * 128 + p) * 1024 + g * 32 + half * 16;
#pragma unroll
  for (int j = 0; j < 16; ++j) {
    float a = e[j] * inv;
    arow_out[j] = a;
    Arow[p][half * 16 + j] = a;
  }
  __syncthreads();

  float4 acc4[8];
#pragma unroll
  for (int i = 0; i < 8; ++i) acc4[i] = (float4){0.f, 0.f, 0.f, 0.f};
#pragma unroll
  for (int t = 0; t < 32; ++t) {
    const float av = Arow[p][t];
#pragma unroll
    for (int d4 = 0; d4 < 8; ++d4) {
      float4 v = *(const float4*)&Vsh[t][half * 32 + d4 * 4];
      acc4[d4].x += av * v.x;
      acc4[d4].y += av * v.y;
      acc4[d4].z += av * v.z;
      acc4[d4].w += av * v.w;
    }
  }
  _Float16* crow = ctx + (size_t)(g * 128 + p) * 1024 + h * 64 + half * 32;
#pragma unroll
  for (int i = 0; i < 4; ++i) {
    f16x8 hv;
    float4 lo = acc4[i * 2], hi = acc4[i * 2 + 1];
    hv[0] = (_Float16)lo.x; hv[1] = (_Float16)lo.y;
    hv[2] = (_Float16)lo.z; hv[3] = (_Float16)lo.w;
    hv[4] = (_Float16)hi.x; hv[5] = (_Float16)hi.y;
    hv[6] = (_Float16)hi.z; hv[7] = (_Float16)hi.w;
    *(f16x8*)&crow[i * 8] = hv;
  }
}

// ---------------- launch ----------------
extern "C" void kernel_launch(void* const* d_in, const int* in_sizes, int n_in,
                              void* d_out, int out_size, void* d_ws, size_t ws_size,
                              hipStream_t stream) {
  const float* V_token = (const float*)d_in[0];
  const float* L_token = (const float*)d_in[1];
  const float* Wq_w = (const float*)d_in[4];
  const float* Wq_b = (const float*)d_in[5];
  const float* Wk_w = (const float*)d_in[6];
  const float* Wk_b = (const float*)d_in[7];
  const float* Wv_w = (const float*)d_in[8];
  const float* Wv_b = (const float*)d_in[9];
  const float* Wo_w = (const float*)d_in[10];
  const float* Wo_b = (const float*)d_in[11];
  const float* Wm_w = (const float*)d_in[12];
  const float* Wm_b = (const float*)d_in[13];
  const float* Wv2_w = (const float*)d_in[14];
  const float* Wv2_b = (const float*)d_in[15];

  char* ws = (char*)d_ws;
  _Float16* hV = (_Float16*)ws;   ws += (size_t)4096 * 1024 * 2;
  _Float16* hL = (_Float16*)ws;   ws += (size_t)1024 * 1024 * 2;
  _Float16* hWq = (_Float16*)ws;  ws += (size_t)1024 * 1024 * 2;
  _Float16* hWk = (_Float16*)ws;  ws += (size_t)1024 * 1024 * 2;
  _Float16* hWv = (_Float16*)ws;  ws += (size_t)1024 * 1024 * 2;
  _Float16* hWo = (_Float16*)ws;  ws += (size_t)1024 * 1024 * 2;
  _Float16* hWm = (_Float16*)ws;  ws += (size_t)1024 * 1024 * 2;
  _Float16* hWv2 = (_Float16*)ws; ws += (size_t)1024 * 1024 * 2;
  _Float16* Qh = (_Float16*)ws;   ws += (size_t)4096 * 1024 * 2;
  _Float16* Kh = (_Float16*)ws;   ws += (size_t)1024 * 1024 * 2;
  _Float16* Vh = (_Float16*)ws;   ws += (size_t)1024 * 1024 * 2;
  _Float16* ctx = (_Float16*)ws;  ws += (size_t)4096 * 1024 * 2;
  _Float16* outh = (_Float16*)ws; ws += (size_t)4096 * 1024 * 2;

  float* mu = (float*)d_out;
  float* logv = mu + (size_t)4096 * 1024;
  float* attn = mu + (size_t)2 * 4096 * 1024;

  // 1: all f32->f16 conversions in one launch
  CvtArgs ca;
  ca.src[0] = V_token; ca.dst[0] = hV;  ca.n4[0] = 4096 * 1024 / 4;
  ca.src[1] = L_token; ca.dst[1] = hL;  ca.n4[1] = 1024 * 1024 / 4;
  ca.src[2] = Wq_w;  ca.dst[2] = hWq;  ca.n4[2] = 1024 * 1024 / 4;
  ca.src[3] = Wk_w;  ca.dst[3] = hWk;  ca.n4[3] = 1024 * 1024 / 4;
  ca.src[4] = Wv_w;  ca.dst[4] = hWv;  ca.n4[4] = 1024 * 1024 / 4;
  ca.src[5] = Wo_w;  ca.dst[5] = hWo;  ca.n4[5] = 1024 * 1024 / 4;
  ca.src[6] = Wm_w;  ca.dst[6] = hWm;  ca.n4[6] = 1024 * 1024 / 4;
  ca.src[7] = Wv2_w; ca.dst[7] = hWv2; ca.n4[7] = 1024 * 1024 / 4;
  hipLaunchKernelGGL(cvt_all, dim3(128, 8), dim3(256), 0, stream, ca);

  // 2: fill attn[0:8] (dispatched first) + Q,K,V GEMMs
  hipLaunchKernelGGL(gemm_qkv_fill, dim3(640), dim3(256), 0, stream,
                     hV, hL, hWq, hWk, hWv, Wq_b, Wk_b, Wv_b, Qh, Kh, Vh, attn);

  // 3: attention -> attn nonzero blocks (d_out) + ctx (fp16)
  hipLaunchKernelGGL(attn_kernel, dim3(32, 16), dim3(256), 0, stream, Qh, Kh, Vh, attn, ctx);

  // 4: out = ctx @ Wo^T + bo (fp16 out)
  hipLaunchKernelGGL(gemm_wo, dim3(256), dim3(256), 0, stream, ctx, hWo, Wo_b, outh);

  // 5: skip-fill attn[8:16] (dispatched first) + mu/log_var GEMMs
  hipLaunchKernelGGL(gemm_mv_fill, dim3(768), dim3(256), 0, stream,
                     outh, hWm, hWv2, Wm_b, Wv2_b, mu, logv, attn);
}